// Round 11
// baseline (552.089 us; speedup 1.0000x reference)
//
#include <hip/hip_runtime.h>
#include <hip/hip_cooperative_groups.h>
#include <stdint.h>

namespace cg = cooperative_groups;

typedef unsigned short u16;
typedef unsigned int u32;
typedef __attribute__((ext_vector_type(8))) short short8;
typedef __attribute__((ext_vector_type(4))) short short4v;
typedef __attribute__((ext_vector_type(4))) float f32x4;

#define HW 64
#define CH 256
#define NIMG 16
#define NPIX (NIMG*HW*HW)   // 65536 pixels

static __device__ __forceinline__ u16 f2bf(float f){
  u32 u = __float_as_uint(f);
  u32 r = u + 0x7FFFu + ((u >> 16) & 1u);   // RNE
  return (u16)(r >> 16);
}
static __device__ __forceinline__ float bf2f(u16 h){
  return __uint_as_float(((u32)h) << 16);
}
static __device__ __forceinline__ u32 relu_pk(u32 w){   // relu two packed bf16
  u32 lo = (w & 0x00008000u) ? 0u : (w & 0x0000FFFFu);
  u32 hi = (w & 0x80000000u) ? 0u : (w & 0xFFFF0000u);
  return lo | hi;
}

// LDS-visibility barrier (no vmem drain)
#define BARRIER_KEEP_VMEM() do { \
  asm volatile("s_waitcnt lgkmcnt(0)" ::: "memory"); \
  __builtin_amdgcn_s_barrier(); \
} while (0)
// quarter-end: drain gload_lds (vmcnt) + ds ops, then barrier.
#define SEG_SYNC() do { \
  asm volatile("s_waitcnt vmcnt(0)" ::: "memory"); \
  asm volatile("s_waitcnt lgkmcnt(0)" ::: "memory"); \
  __builtin_amdgcn_s_barrier(); \
} while (0)

// ---------------- weight prep ----------------
// W1T[j][c] bf16.
// W2T: 12 blocks bt=q*3+dr of 12288 u16; within a block, linear order
// (row = dc*64 + n, 16B unit u) holds original channels (u ^ (row&7)) --
// XOR involution baked in so a LINEAR global->LDS copy yields the swizzled
// layout. Blocks q*3..q*3+2 are the 9 taps of input-quarter q.
__global__ void k_prep(const float* __restrict__ w1, const float* __restrict__ w2,
                       u16* __restrict__ W1T, u16* __restrict__ W2T){
  int idx = blockIdx.x*256 + threadIdx.x;   // 640*256 = 163840 exactly
  if (idx < 16384){
    int j = idx >> 8, c = idx & 255;
    W1T[idx] = f2bf(w1[c*64 + j]);          // w1 is (1,1,256,64) -> [c][j]
  } else {
    int o = idx - 16384;                    // 0..147455
    int bt  = o / 12288;                    // q*3 + dr
    int rem = o - bt*12288;
    int row = rem >> 6;                     // 0..191 = dc*64 + n
    int j   = rem & 63;
    int u   = j >> 3, e = j & 7;
    int q = bt / 3, dr = bt - q*3;
    int dc = row >> 6, n = row & 63;
    int cin = q*64 + ((u ^ (row & 7)) << 3) + e;
    int tap = dr*3 + dc;
    W2T[o] = f2bf(w2[(tap*256 + cin)*64 + n]);  // w2 is (3,3,256,64)
  }
}

// ---------------- phase 1: fused 4-step pointwise gradual update ----------------
__global__ __launch_bounds__(256) void k_phase1(const float* __restrict__ x,
    const u16* __restrict__ W1T, const float* __restrict__ b1, u16* __restrict__ B){
  __shared__ u16 At[64*264];    // 64 px x 256 ch (+8 pad)  33792 B
  __shared__ u16 Ws[64*264];    // W1T staged [n][k] (+8)   33792 B
  const int tid = threadIdx.x;
  const long pbase = (long)blockIdx.x * 64;

  #pragma unroll
  for (int it=0; it<16; ++it){
    int idx = it*256 + tid;
    int px = idx >> 6;
    int c4 = (idx & 63) << 2;
    const float4 v = *(const float4*)(x + (pbase + px)*CH + c4);
    short4v s;
    s[0] = (short)f2bf(v.x); s[1] = (short)f2bf(v.y);
    s[2] = (short)f2bf(v.z); s[3] = (short)f2bf(v.w);
    *(short4v*)&At[px*264 + c4] = s;
  }
  #pragma unroll
  for (int it=0; it<8; ++it){
    int idx = it*256 + tid;
    int n = idx >> 5;
    int c8 = (idx & 31) << 3;
    *(uint4*)&Ws[n*264 + c8] = *(const uint4*)&W1T[n*256 + c8];
  }
  __syncthreads();

  const int wave = tid >> 6, lane = tid & 63;
  const int m = lane & 15, quad = lane >> 4;
  const int abase = (wave*16 + m)*264 + quad*8;
  int bbase[4];
  #pragma unroll
  for (int nt=0; nt<4; ++nt) bbase[nt] = (nt*16 + m)*264 + quad*8;
  float b1v[4];
  #pragma unroll
  for (int nt=0; nt<4; ++nt) b1v[nt] = b1[nt*16 + m];

  for (int stepi=0; stepi<4; ++stepi){
    f32x4 acc[4];
    #pragma unroll
    for (int b=0;b<4;++b) acc[b] = 0.f;
    #pragma unroll
    for (int kk=0; kk<8; ++kk){
      const int ko = kk*32;
      short8 af = *(const short8*)&At[abase + ko];
      short8 bf[4];
      #pragma unroll
      for (int nt=0; nt<4; ++nt) bf[nt] = *(const short8*)&Ws[bbase[nt] + ko];
      #pragma unroll
      for (int nt=0; nt<4; ++nt)
        acc[nt] = __builtin_amdgcn_mfma_f32_16x16x32_bf16(af, bf[nt], acc[nt], 0,0,0);
    }
    #pragma unroll
    for (int nt=0; nt<4; ++nt){
      #pragma unroll
      for (int r=0; r<4; ++r){
        int px = wave*16 + quad*4 + r;
        At[px*264 + stepi*64 + nt*16 + m] = f2bf(acc[nt][r] + b1v[nt]);
      }
    }
    // no barrier: each wave reads/writes only its own 16 px
  }
  __syncthreads();
  #pragma unroll
  for (int it=0; it<16; ++it){
    int idx = it*256 + tid;
    int px = idx >> 6;
    int c4 = (idx & 63) << 2;
    uint2 v = *(const uint2*)&At[px*264 + c4];
    v.x = relu_pk(v.x); v.y = relu_pk(v.y);
    *(uint2*)&B[(pbase + px)*CH + c4] = v;
  }
}

// ---------------- phase 2 (FUSED): all 4 gradual-update steps, cooperative ----------------
// One dispatch: 256 blocks x 512 threads = exactly 1 block/CU co-resident.
// for s=0..3: quarter-granular full conv (r10's verified body) -> write Bout
// quarter s -> threadfence + grid.sync. Tests the dispatch-envelope hypothesis:
// 4x~39us dispatches where internal work is provably NOT the limit (r8/r9/r10
// invariance) -> fused pays launch/setup/L2-warm/head-tail skew once, not 4x.
// LDS = 49248 + 73728 = 123 KB.
__global__ __launch_bounds__(512) void k_phase2f(const u16* __restrict__ B,
    u16* __restrict__ Bout, const u16* __restrict__ W2T, const float* __restrict__ b2){
  __shared__ u16 As[324*76];      // 18x18 halo px x 64 ch (stride 76)  49248 B
  __shared__ u16 Wq[576*64];      // 9 taps x 64 out x 64 in, swizzled  73728 B
  const int tid = threadIdx.x;
  const int bid = blockIdx.x;
  const int img = bid >> 4;
  const int R0 = ((bid >> 2) & 3) * 16;
  const int C0 = (bid & 3) * 16;

  const int wave = tid >> 6, lane = tid & 63;
  const int m = lane & 15, quad = lane >> 4;

  cg::grid_group grid = cg::this_grid();

  uint4 ra[6];

  auto load_as = [&](int q, int step, uint4* r4){
    #pragma unroll
    for (int it=0; it<6; ++it){
      int idx = it*512 + tid;
      uint4 v = make_uint4(0u,0u,0u,0u);
      if (idx < 2592){
        int px = idx >> 3, ck = idx & 7;
        int hr = px / 18, hc = px - hr*18;
        int r = R0 + hr - 1, c = C0 + hc - 1;
        if ((unsigned)r < 64u && (unsigned)c < 64u){
          const u16* src = (q < step) ? Bout : B;   // B already relu'd by phase1
          v = *(const uint4*)&src[((((size_t)img*64)+r)*64 + c)*CH + q*64 + ck*8];
        }
      }
      r4[it] = v;
    }
  };
  auto store_as = [&](const uint4* r4){
    #pragma unroll
    for (int it=0; it<6; ++it){
      int idx = it*512 + tid;
      if (idx < 2592){
        int px = idx >> 3, ck = idx & 7;
        *(uint4*)&As[px*76 + ck*8] = r4[it];
      }
    }
  };
  // stage quarter q's full 9-tap weight set: 72 chunks of 1024 B (async to LDS)
  auto gload_wq = [&](int q){
    const u16* wbase = W2T + (size_t)q*36864;
    #pragma unroll
    for (int it=0; it<9; ++it){
      int chunk = wave*9 + it;                          // 0..71
      const u16* g = wbase + chunk*512 + lane*8;
      __builtin_amdgcn_global_load_lds(
        (const __attribute__((address_space(1))) void*)g,
        (__attribute__((address_space(3))) void*)&Wq[chunk*512],
        16, 0, 0);
    }
  };

  float b2v[4];
  #pragma unroll
  for (int nt=0; nt<4; ++nt) b2v[nt] = b2[nt*16 + m];

  for (int s = 0; s < 4; ++s){
    // step prologue: stage quarter-0 weights + activations
    gload_wq(0);
    load_as(0, s, ra); store_as(ra);
    __syncthreads();   // full drain (prologue)

    f32x4 acc[2][4];
    #pragma unroll
    for (int a=0;a<2;++a){
      #pragma unroll
      for (int b=0;b<4;++b) acc[a][b] = 0.f;
    }

    for (int q = 0; q < 4; ++q){
      if (q < 3) load_as(q+1, s, ra);   // in flight across the whole quarter

      // all 9 taps x 2 kk, no barriers inside
      #pragma unroll
      for (int dr=0; dr<3; ++dr){
        #pragma unroll
        for (int dc=0; dc<3; ++dc){
          #pragma unroll
          for (int kk=0; kk<2; ++kk){
            short8 af[2], bf[4];
            #pragma unroll
            for (int mt=0; mt<2; ++mt){
              int rt = wave + mt*8;
              af[mt] = *(const short8*)&As[((rt+dr)*18 + m + dc)*76 + kk*32 + quad*8];
            }
            #pragma unroll
            for (int nt=0; nt<4; ++nt){
              int row  = dr*192 + dc*64 + nt*16 + m;   // row&7 == m&7
              int unit = (kk*4 + quad) ^ (m & 7);
              bf[nt] = *(const short8*)&Wq[row*64 + unit*8];
            }
            #pragma unroll
            for (int mt=0; mt<2; ++mt){
              #pragma unroll
              for (int nt=0; nt<4; ++nt)
                acc[mt][nt] = __builtin_amdgcn_mfma_f32_16x16x32_bf16(af[mt], bf[nt], acc[mt][nt], 0,0,0);
            }
          }
        }
      }

      if (q < 3){
        BARRIER_KEEP_VMEM();   // all waves done reading As(q) + Wq(q)
        gload_wq(q+1);         // async; flight overlapped by store_as ds_writes
        store_as(ra);          // compiler vmcnt-waits on ra only
        SEG_SYNC();            // Wq landed + As stores visible
      }
    }

    // epilogue: write Bout quarter s
    #pragma unroll
    for (int mt=0; mt<2; ++mt){
      #pragma unroll
      for (int nt=0; nt<4; ++nt){
        #pragma unroll
        for (int r=0; r<4; ++r){
          int row = R0 + wave + mt*8;
          int col = C0 + quad*4 + r;
          size_t gi = ((((size_t)img*64 + row)*64) + col)*CH + s*64 + nt*16 + m;
          Bout[gi] = f2bf(acc[mt][nt][r] + b2v[nt]);
        }
      }
    }

    if (s < 3){
      __threadfence();   // device-scope: Bout visible across XCDs
      grid.sync();       // all blocks' quarter-s writes complete
    }
  }
}

// ---------------- phase 3: per-pixel affine recurrence + residual ----------------
// 16 lanes per pixel, 16 channels each; serial chains 16 steps; x loads hoisted.
__global__ __launch_bounds__(256) void k_phase3(const u16* __restrict__ Bout,
    const float* __restrict__ w3, const float* __restrict__ b3,
    const float* __restrict__ x, float* __restrict__ out){
  __shared__ float w3s[16*17];  // stride-17: conflict-free
  const int tid = threadIdx.x;
  {
    int sseg = tid >> 4, c = tid & 15;
    w3s[sseg*17 + c] = w3[tid];
  }
  const float b3v = b3[0];
  __syncthreads();

  const int g   = blockIdx.x*256 + tid;   // 4096 blocks * 256 = 16*NPIX
  const int px  = g >> 4;
  const int seg = g & 15;
  const size_t cbase = (size_t)px*CH + seg*16;
  const float* wseg = &w3s[seg*17];

  uint4 d[2];
  #pragma unroll
  for (int i=0; i<2; ++i){
    uint4 v = *(const uint4*)&Bout[cbase + i*8];
    v.x = relu_pk(v.x); v.y = relu_pk(v.y); v.z = relu_pk(v.z); v.w = relu_pk(v.w);
    d[i] = v;
  }
  float4 xv[4];
  #pragma unroll
  for (int i=0; i<4; ++i) xv[i] = *(const float4*)&x[cbase + i*4];

  float s0=0.f, s1=0.f;
  #pragma unroll
  for (int i=0; i<2; ++i){
    const u32* p = (const u32*)&d[i];
    #pragma unroll
    for (int k=0; k<4; ++k){
      u32 w = p[k];
      int c = i*8 + k*2;
      s0 += bf2f((u16)(w & 0xFFFF)) * wseg[c];
      s1 += bf2f((u16)(w >> 16))    * wseg[c+1];
    }
  }
  float dot = s0 + s1;
  dot += __shfl_xor(dot, 1, 16);
  dot += __shfl_xor(dot, 2, 16);
  dot += __shfl_xor(dot, 4, 16);
  dot += __shfl_xor(dot, 8, 16);
  const float S0 = b3v + dot;

  float alpha = 1.f, beta = 0.f;
  #pragma unroll
  for (int i=0; i<2; ++i){
    const u32* p = (const u32*)&d[i];
    #pragma unroll
    for (int k=0; k<4; ++k){
      u32 wv = p[k];
      int c = i*8 + k*2;
      float w_a = wseg[c];
      float w_b = wseg[c+1];
      float a_a = bf2f((u16)(wv & 0xFFFF));
      float a_b = bf2f((u16)(wv >> 16));
      beta  = (1.f + w_a)*beta  - w_a*a_a;
      alpha = (1.f + w_a)*alpha;
      beta  = (1.f + w_b)*beta  - w_b*a_b;
      alpha = (1.f + w_b)*alpha;
    }
  }

  float a = alpha, b = beta;
  #pragma unroll
  for (int off=1; off<16; off<<=1){
    float pa = __shfl_up(a, off, 16);
    float pb = __shfl_up(b, off, 16);
    if (seg >= off){ b = a*pb + b; a = a*pa; }
  }
  float ea = __shfl_up(a, 1, 16);
  float eb = __shfl_up(b, 1, 16);
  float Sp = (seg == 0) ? S0 : (ea*S0 + eb);

  #pragma unroll
  for (int i=0; i<2; ++i){
    const u32* p = (const u32*)&d[i];
    float xs[8] = {xv[2*i].x, xv[2*i].y, xv[2*i].z, xv[2*i].w,
                   xv[2*i+1].x, xv[2*i+1].y, xv[2*i+1].z, xv[2*i+1].w};
    float os[8];
    #pragma unroll
    for (int k=0; k<4; ++k){
      u32 wv = p[k];
      int c = i*8 + k*2;
      float w_a = wseg[c];
      float w_b = wseg[c+1];
      float a_a = bf2f((u16)(wv & 0xFFFF));
      float a_b = bf2f((u16)(wv >> 16));
      os[k*2]   = Sp + xs[k*2];
      Sp = (1.f + w_a)*Sp - w_a*a_a;
      os[k*2+1] = Sp + xs[k*2+1];
      Sp = (1.f + w_b)*Sp - w_b*a_b;
    }
    float4 o0, o1;
    o0.x=os[0]; o0.y=os[1]; o0.z=os[2]; o0.w=os[3];
    o1.x=os[4]; o1.y=os[5]; o1.z=os[6]; o1.w=os[7];
    *(float4*)&out[cbase + i*8]     = o0;
    *(float4*)&out[cbase + i*8 + 4] = o1;
  }
}

extern "C" void kernel_launch(void* const* d_in, const int* in_sizes, int n_in,
                              void* d_out, int out_size, void* d_ws, size_t ws_size,
                              hipStream_t stream){
  const float* x  = (const float*)d_in[0];
  const float* w1 = (const float*)d_in[1];
  const float* b1 = (const float*)d_in[2];
  const float* w2 = (const float*)d_in[3];
  const float* b2 = (const float*)d_in[4];
  const float* w3 = (const float*)d_in[5];
  const float* b3 = (const float*)d_in[6];
  float* out = (float*)d_out;

  // workspace carve: B(relu'd) 32MB | Bout 32MB | W1T 32KB | W2T 288KB
  u16* B    = (u16*)d_ws;
  u16* Bout = B    + (size_t)NPIX*CH;
  u16* W1T  = Bout + (size_t)NPIX*CH;
  u16* W2T  = W1T  + 16384;

  hipLaunchKernelGGL(k_prep,   dim3(640),  dim3(256), 0, stream, w1, w2, W1T, W2T);
  hipLaunchKernelGGL(k_phase1, dim3(1024), dim3(256), 0, stream, x, W1T, b1, B);

  {
    const u16* Bc = B; u16* Bo = Bout; const u16* Wc = W2T; const float* b2c = b2;
    void* args[] = {(void*)&Bc, (void*)&Bo, (void*)&Wc, (void*)&b2c};
    hipLaunchCooperativeKernel((const void*)k_phase2f, dim3(256), dim3(512),
                               args, 0, stream);
  }

  hipLaunchKernelGGL(k_phase3, dim3(4096), dim3(256), 0, stream, Bout, w3, b3, x, out);
}

// Round 12
// 249.271 us; speedup vs baseline: 2.2148x; 2.2148x over previous
//
#include <hip/hip_runtime.h>
#include <stdint.h>

typedef unsigned short u16;
typedef unsigned int u32;
typedef __attribute__((ext_vector_type(8))) short short8;
typedef __attribute__((ext_vector_type(4))) short short4v;
typedef __attribute__((ext_vector_type(4))) float f32x4;

#define HW 64
#define CH 256
#define NIMG 16
#define NPIX (NIMG*HW*HW)   // 65536 pixels

static __device__ __forceinline__ u16 f2bf(float f){
  u32 u = __float_as_uint(f);
  u32 r = u + 0x7FFFu + ((u >> 16) & 1u);   // RNE
  return (u16)(r >> 16);
}
static __device__ __forceinline__ float bf2f(u16 h){
  return __uint_as_float(((u32)h) << 16);
}
static __device__ __forceinline__ u32 relu_pk(u32 w){   // relu two packed bf16
  u32 lo = (w & 0x00008000u) ? 0u : (w & 0x0000FFFFu);
  u32 hi = (w & 0x80000000u) ? 0u : (w & 0xFFFF0000u);
  return lo | hi;
}

// LDS-visibility barrier (no vmem drain)
#define BARRIER_KEEP_VMEM() do { \
  asm volatile("s_waitcnt lgkmcnt(0)" ::: "memory"); \
  __builtin_amdgcn_s_barrier(); \
} while (0)
// seg-end: drain gload_lds (vmcnt) + ds ops, then barrier.
#define SEG_SYNC() do { \
  asm volatile("s_waitcnt vmcnt(0)" ::: "memory"); \
  asm volatile("s_waitcnt lgkmcnt(0)" ::: "memory"); \
  __builtin_amdgcn_s_barrier(); \
} while (0)

// ---------------- weight prep ----------------
// W1T[j][c] bf16.
// W2T: 12 blocks bt=q*3+dr of 12288 u16; within a block, linear order
// (row = dc*64 + n, 16B unit u) holds original channels (u ^ (row&7)) --
// XOR involution baked in so a LINEAR global->LDS copy yields the swizzled layout.
__global__ void k_prep(const float* __restrict__ w1, const float* __restrict__ w2,
                       u16* __restrict__ W1T, u16* __restrict__ W2T){
  int idx = blockIdx.x*256 + threadIdx.x;   // 640*256 = 163840 exactly
  if (idx < 16384){
    int j = idx >> 8, c = idx & 255;
    W1T[idx] = f2bf(w1[c*64 + j]);          // w1 is (1,1,256,64) -> [c][j]
  } else {
    int o = idx - 16384;                    // 0..147455
    int bt  = o / 12288;                    // q*3 + dr
    int rem = o - bt*12288;
    int row = rem >> 6;                     // 0..191 = dc*64 + n
    int j   = rem & 63;
    int u   = j >> 3, e = j & 7;
    int q = bt / 3, dr = bt - q*3;
    int dc = row >> 6, n = row & 63;
    int cin = q*64 + ((u ^ (row & 7)) << 3) + e;
    int tap = dr*3 + dc;
    W2T[o] = f2bf(w2[(tap*256 + cin)*64 + n]);  // w2 is (3,3,256,64)
  }
}

// ---------------- phase 1: fused 4-step pointwise gradual update ----------------
__global__ __launch_bounds__(256) void k_phase1(const float* __restrict__ x,
    const u16* __restrict__ W1T, const float* __restrict__ b1, u16* __restrict__ B){
  __shared__ u16 At[64*264];    // 64 px x 256 ch (+8 pad)  33792 B
  __shared__ u16 Ws[64*264];    // W1T staged [n][k] (+8)   33792 B
  const int tid = threadIdx.x;
  const long pbase = (long)blockIdx.x * 64;

  #pragma unroll
  for (int it=0; it<16; ++it){
    int idx = it*256 + tid;
    int px = idx >> 6;
    int c4 = (idx & 63) << 2;
    const float4 v = *(const float4*)(x + (pbase + px)*CH + c4);
    short4v s;
    s[0] = (short)f2bf(v.x); s[1] = (short)f2bf(v.y);
    s[2] = (short)f2bf(v.z); s[3] = (short)f2bf(v.w);
    *(short4v*)&At[px*264 + c4] = s;
  }
  #pragma unroll
  for (int it=0; it<8; ++it){
    int idx = it*256 + tid;
    int n = idx >> 5;
    int c8 = (idx & 31) << 3;
    *(uint4*)&Ws[n*264 + c8] = *(const uint4*)&W1T[n*256 + c8];
  }
  __syncthreads();

  const int wave = tid >> 6, lane = tid & 63;
  const int m = lane & 15, quad = lane >> 4;
  const int abase = (wave*16 + m)*264 + quad*8;
  int bbase[4];
  #pragma unroll
  for (int nt=0; nt<4; ++nt) bbase[nt] = (nt*16 + m)*264 + quad*8;
  float b1v[4];
  #pragma unroll
  for (int nt=0; nt<4; ++nt) b1v[nt] = b1[nt*16 + m];

  for (int stepi=0; stepi<4; ++stepi){
    f32x4 acc[4];
    #pragma unroll
    for (int b=0;b<4;++b) acc[b] = 0.f;
    #pragma unroll
    for (int kk=0; kk<8; ++kk){
      const int ko = kk*32;
      short8 af = *(const short8*)&At[abase + ko];
      short8 bf[4];
      #pragma unroll
      for (int nt=0; nt<4; ++nt) bf[nt] = *(const short8*)&Ws[bbase[nt] + ko];
      #pragma unroll
      for (int nt=0; nt<4; ++nt)
        acc[nt] = __builtin_amdgcn_mfma_f32_16x16x32_bf16(af, bf[nt], acc[nt], 0,0,0);
    }
    #pragma unroll
    for (int nt=0; nt<4; ++nt){
      #pragma unroll
      for (int r=0; r<4; ++r){
        int px = wave*16 + quad*4 + r;
        At[px*264 + stepi*64 + nt*16 + m] = f2bf(acc[nt][r] + b1v[nt]);
      }
    }
    // no barrier: each wave reads/writes only its own 16 px
  }
  __syncthreads();
  #pragma unroll
  for (int it=0; it<16; ++it){
    int idx = it*256 + tid;
    int px = idx >> 6;
    int c4 = (idx & 63) << 2;
    uint2 v = *(const uint2*)&At[px*264 + c4];
    v.x = relu_pk(v.x); v.y = relu_pk(v.y);
    *(uint2*)&B[(pbase + px)*CH + c4] = v;
  }
}

// ---------------- phase 2: one 3x3 gradual-update step (launched 4x) ----------------
// 16x16 px tiles, 256 blocks, 512 threads (8 waves). Round-7 verified pipeline
// (gload_lds weight relay, 12-seg, SEG_SYNC) + XCD-contiguous block swizzle:
// bid = (bid0&7)*32 + bid0>>3 (bijective, 256%8==0). Default round-robin puts
// halo-sharing adjacent tiles on different XCDs -> every halo load misses the
// local L2 (FETCH 21 MB vs ~8 ideal). Swizzled: each XCD owns a contiguous run
// of 32 tiles = exactly 2 images; all halo re-reads are XCD-local (1 MB/quarter
// working set << 4 MB L2).
__global__ __launch_bounds__(512) void k_phase2(const u16* __restrict__ B,
    u16* __restrict__ Bout, const u16* __restrict__ W2T, const float* __restrict__ b2,
    const int step){
  __shared__ u16 As[324*76];      // 18x18 halo px x 64 ch (stride 76)  49248 B
  __shared__ u16 Ws[2][192*64];   // [dc*64+n] x 64 ch, swizzled, linear 2x24576 B
  const int tid = threadIdx.x;
  const int bid0 = blockIdx.x;
  const int bid = ((bid0 & 7) << 5) + (bid0 >> 3);   // XCD-contiguous remap
  const int img = bid >> 4;
  const int R0 = ((bid >> 2) & 3) * 16;
  const int C0 = (bid & 3) * 16;

  const int wave = tid >> 6, lane = tid & 63;
  const int m = lane & 15, quad = lane >> 4;

  uint4 ra[6];

  auto load_as = [&](int q, uint4* r4){
    #pragma unroll
    for (int it=0; it<6; ++it){
      int idx = it*512 + tid;
      uint4 v = make_uint4(0u,0u,0u,0u);
      if (idx < 2592){
        int px = idx >> 3, ck = idx & 7;
        int hr = px / 18, hc = px - hr*18;
        int r = R0 + hr - 1, c = C0 + hc - 1;
        if ((unsigned)r < 64u && (unsigned)c < 64u){
          const u16* src = (q < step) ? Bout : B;   // B already relu'd by phase1
          v = *(const uint4*)&src[((((size_t)img*64)+r)*64 + c)*CH + q*64 + ck*8];
        }
      }
      r4[it] = v;
    }
  };
  auto store_as = [&](const uint4* r4){
    #pragma unroll
    for (int it=0; it<6; ++it){
      int idx = it*512 + tid;
      if (idx < 2592){
        int px = idx >> 3, ck = idx & 7;
        *(uint4*)&As[px*76 + ck*8] = r4[it];
      }
    }
  };
  // stage one tap-triplet (24576 B) via async global->LDS, 16B/lane.
  auto gload_ws = [&](int bt, int buf){
    #pragma unroll
    for (int it=0; it<3; ++it){
      int chunk = wave*3 + it;                          // 0..23, 1024 B each
      const u16* g2 = W2T + (size_t)bt*12288 + chunk*512 + lane*8;
      __builtin_amdgcn_global_load_lds(
        (const __attribute__((address_space(1))) void*)g2,
        (__attribute__((address_space(3))) void*)&Ws[buf][chunk*512],
        16, 0, 0);
    }
  };

  // prologue: stage seg0 weights + quarter-0 As; full drain acceptable here
  gload_ws(0, 0);
  load_as(0, ra); store_as(ra);
  __syncthreads();

  f32x4 acc[2][4];
  #pragma unroll
  for (int a=0;a<2;++a){
    #pragma unroll
    for (int b=0;b<4;++b) acc[a][b] = 0.f;
  }

  #pragma unroll
  for (int seg = 0; seg < 12; ++seg){
    const int q  = seg / 3;
    const int dr = seg % 3;

    if (seg <= 10) gload_ws(seg+1, (seg+1)&1);   // dest buf idle this seg
    if (dr == 1 && q < 3) load_as(q+1, ra);

    const u16* wsb = Ws[seg & 1];
    #pragma unroll
    for (int dc=0; dc<3; ++dc){
      #pragma unroll
      for (int kk=0; kk<2; ++kk){
        short8 af[2], bf[4];
        #pragma unroll
        for (int mt=0; mt<2; ++mt){
          int rt = wave + mt*8;
          af[mt] = *(const short8*)&As[((rt+dr)*18 + m + dc)*76 + kk*32 + quad*8];
        }
        #pragma unroll
        for (int nt=0; nt<4; ++nt){
          int row  = dc*64 + nt*16 + m;
          int unit = (kk*4 + quad) ^ (m & 7);   // row&7 == m&7
          bf[nt] = *(const short8*)&wsb[row*64 + unit*8];
        }
        #pragma unroll
        for (int mt=0; mt<2; ++mt){
          #pragma unroll
          for (int nt=0; nt<4; ++nt)
            acc[mt][nt] = __builtin_amdgcn_mfma_f32_16x16x32_bf16(af[mt], bf[nt], acc[mt][nt], 0,0,0);
        }
      }
    }

    if (dr == 2 && q < 3){
      BARRIER_KEEP_VMEM();     // all waves done reading As(q)
      store_as(ra);            // compiler vmcnt-waits on ra only
    }
    if (seg < 11) SEG_SYNC();  // next-seg Ws landed + ds stores visible
  }

  float b2v[4];
  #pragma unroll
  for (int nt=0; nt<4; ++nt) b2v[nt] = b2[nt*16 + m];
  #pragma unroll
  for (int mt=0; mt<2; ++mt){
    #pragma unroll
    for (int nt=0; nt<4; ++nt){
      #pragma unroll
      for (int r=0; r<4; ++r){
        int row = R0 + wave + mt*8;
        int col = C0 + quad*4 + r;
        size_t gi = ((((size_t)img*64 + row)*64) + col)*CH + step*64 + nt*16 + m;
        Bout[gi] = f2bf(acc[mt][nt][r] + b2v[nt]);
      }
    }
  }
}

// ---------------- phase 3: per-pixel affine recurrence + residual ----------------
// 16 lanes per pixel, 16 channels each; serial chains 16 steps; x loads hoisted.
__global__ __launch_bounds__(256) void k_phase3(const u16* __restrict__ Bout,
    const float* __restrict__ w3, const float* __restrict__ b3,
    const float* __restrict__ x, float* __restrict__ out){
  __shared__ float w3s[16*17];  // stride-17: conflict-free
  const int tid = threadIdx.x;
  {
    int sseg = tid >> 4, c = tid & 15;
    w3s[sseg*17 + c] = w3[tid];
  }
  const float b3v = b3[0];
  __syncthreads();

  const int g   = blockIdx.x*256 + tid;   // 4096 blocks * 256 = 16*NPIX
  const int px  = g >> 4;
  const int seg = g & 15;
  const size_t cbase = (size_t)px*CH + seg*16;
  const float* wseg = &w3s[seg*17];

  uint4 d[2];
  #pragma unroll
  for (int i=0; i<2; ++i){
    uint4 v = *(const uint4*)&Bout[cbase + i*8];
    v.x = relu_pk(v.x); v.y = relu_pk(v.y); v.z = relu_pk(v.z); v.w = relu_pk(v.w);
    d[i] = v;
  }
  float4 xv[4];
  #pragma unroll
  for (int i=0; i<4; ++i) xv[i] = *(const float4*)&x[cbase + i*4];

  float s0=0.f, s1=0.f;
  #pragma unroll
  for (int i=0; i<2; ++i){
    const u32* p = (const u32*)&d[i];
    #pragma unroll
    for (int k=0; k<4; ++k){
      u32 w = p[k];
      int c = i*8 + k*2;
      s0 += bf2f((u16)(w & 0xFFFF)) * wseg[c];
      s1 += bf2f((u16)(w >> 16))    * wseg[c+1];
    }
  }
  float dot = s0 + s1;
  dot += __shfl_xor(dot, 1, 16);
  dot += __shfl_xor(dot, 2, 16);
  dot += __shfl_xor(dot, 4, 16);
  dot += __shfl_xor(dot, 8, 16);
  const float S0 = b3v + dot;

  float alpha = 1.f, beta = 0.f;
  #pragma unroll
  for (int i=0; i<2; ++i){
    const u32* p = (const u32*)&d[i];
    #pragma unroll
    for (int k=0; k<4; ++k){
      u32 wv = p[k];
      int c = i*8 + k*2;
      float w_a = wseg[c];
      float w_b = wseg[c+1];
      float a_a = bf2f((u16)(wv & 0xFFFF));
      float a_b = bf2f((u16)(wv >> 16));
      beta  = (1.f + w_a)*beta  - w_a*a_a;
      alpha = (1.f + w_a)*alpha;
      beta  = (1.f + w_b)*beta  - w_b*a_b;
      alpha = (1.f + w_b)*alpha;
    }
  }

  float a = alpha, b = beta;
  #pragma unroll
  for (int off=1; off<16; off<<=1){
    float pa = __shfl_up(a, off, 16);
    float pb = __shfl_up(b, off, 16);
    if (seg >= off){ b = a*pb + b; a = a*pa; }
  }
  float ea = __shfl_up(a, 1, 16);
  float eb = __shfl_up(b, 1, 16);
  float Sp = (seg == 0) ? S0 : (ea*S0 + eb);

  #pragma unroll
  for (int i=0; i<2; ++i){
    const u32* p = (const u32*)&d[i];
    float xs[8] = {xv[2*i].x, xv[2*i].y, xv[2*i].z, xv[2*i].w,
                   xv[2*i+1].x, xv[2*i+1].y, xv[2*i+1].z, xv[2*i+1].w};
    float os[8];
    #pragma unroll
    for (int k=0; k<4; ++k){
      u32 wv = p[k];
      int c = i*8 + k*2;
      float w_a = wseg[c];
      float w_b = wseg[c+1];
      float a_a = bf2f((u16)(wv & 0xFFFF));
      float a_b = bf2f((u16)(wv >> 16));
      os[k*2]   = Sp + xs[k*2];
      Sp = (1.f + w_a)*Sp - w_a*a_a;
      os[k*2+1] = Sp + xs[k*2+1];
      Sp = (1.f + w_b)*Sp - w_b*a_b;
    }
    float4 o0, o1;
    o0.x=os[0]; o0.y=os[1]; o0.z=os[2]; o0.w=os[3];
    o1.x=os[4]; o1.y=os[5]; o1.z=os[6]; o1.w=os[7];
    *(float4*)&out[cbase + i*8]     = o0;
    *(float4*)&out[cbase + i*8 + 4] = o1;
  }
}

extern "C" void kernel_launch(void* const* d_in, const int* in_sizes, int n_in,
                              void* d_out, int out_size, void* d_ws, size_t ws_size,
                              hipStream_t stream){
  const float* x  = (const float*)d_in[0];
  const float* w1 = (const float*)d_in[1];
  const float* b1 = (const float*)d_in[2];
  const float* w2 = (const float*)d_in[3];
  const float* b2 = (const float*)d_in[4];
  const float* w3 = (const float*)d_in[5];
  const float* b3 = (const float*)d_in[6];
  float* out = (float*)d_out;

  // workspace carve: B(relu'd) 32MB | Bout 32MB | W1T 32KB | W2T 288KB
  u16* B    = (u16*)d_ws;
  u16* Bout = B    + (size_t)NPIX*CH;
  u16* W1T  = Bout + (size_t)NPIX*CH;
  u16* W2T  = W1T  + 16384;

  hipLaunchKernelGGL(k_prep,   dim3(640),  dim3(256), 0, stream, w1, w2, W1T, W2T);
  hipLaunchKernelGGL(k_phase1, dim3(1024), dim3(256), 0, stream, x, W1T, b1, B);
  for (int s = 0; s < 4; ++s)
    hipLaunchKernelGGL(k_phase2, dim3(256), dim3(512), 0, stream, B, Bout, W2T, b2, s);
  hipLaunchKernelGGL(k_phase3, dim3(4096), dim3(256), 0, stream, Bout, w3, b3, x, out);
}